// Round 9
// baseline (1209.518 us; speedup 1.0000x reference)
//
#include <hip/hip_runtime.h>
#include <math.h>

#define INV_SQRT1P 0.99999500003749968754f   // 1/sqrt(1+1e-5)
#define REMOVED  -2.0e38f
#define NEGINIT  -3.0e38f

static __device__ __forceinline__ float lrelu(float f){ return f >= 0.0f ? f : 0.2f*f; }

// ---------------- extract channels: feat (B,131,N) -> out (B,N,Cout) ----------------
__global__ void k_extract(const float* __restrict__ f, float* __restrict__ out, int c0, int Cout){
  int i = blockIdx.x*256 + threadIdx.x;
  int total = 8*Cout*1024;
  if (i >= total) return;
  int n  = i & 1023;
  int bc = i >> 10;
  int c  = bc % Cout;
  int b  = bc / Cout;
  out[((size_t)((b<<10)+n))*Cout + c] = f[((size_t)(b*131 + c0 + c) << 10) + n];
}

// ---------------- row sum of squares: x (8192,C) -> xx (8192) ----------------
__global__ void k_xx(const float* __restrict__ x, float* __restrict__ xx, int C){
  int r = blockIdx.x*256 + threadIdx.x;
  if (r >= 8192) return;
  const float* xr = x + (size_t)r*C;
  float s = 0.f;
  for (int c=0;c<C;c++) s += xr[c]*xr[c];
  xx[r] = s;
}

// ---------------- thin NT GEMM: 32 rows x 64 cols per block, 2x4/thread ----------------
__global__ __launch_bounds__(256) void k_gthin(
    const float* __restrict__ Am, const float* __restrict__ Bm, float* __restrict__ Om,
    int K, int ldo, int wmode, const float* __restrict__ p1, const float* __restrict__ p2, int ep)
{
  __shared__ float As[64][33];   // k-major, conflict-free scalar access
  __shared__ float Bs[64][68];   // k-major + XOR swizzle on col
  int tid = threadIdx.x;
  int tx = tid & 15, ty = tid >> 4;
  int rbase = blockIdx.y*32, cbase = blockIdx.x*64;
  float acc[2][4];
  #pragma unroll
  for (int i=0;i<2;i++){ acc[i][0]=0.f; acc[i][1]=0.f; acc[i][2]=0.f; acc[i][3]=0.f; }

  for (int c0=0; c0<K; c0+=64){
    int cw = K - c0; if (cw > 64) cw = 64;
    #pragma unroll
    for (int p=0; p<2; p++){
      int idx = p*256 + tid;
      int kq = idx & 15, row = idx >> 4;
      const float* src = Am + (size_t)(rbase+row)*K + c0 + kq*4;
      float4 v = {0.f,0.f,0.f,0.f};
      if (kq*4 + 4 <= cw) v = *(const float4*)src;
      else {
        if (kq*4+0 < cw) v.x = src[0];
        if (kq*4+1 < cw) v.y = src[1];
        if (kq*4+2 < cw) v.z = src[2];
        if (kq*4+3 < cw) v.w = src[3];
      }
      As[kq*4+0][row]=v.x; As[kq*4+1][row]=v.y; As[kq*4+2][row]=v.z; As[kq*4+3][row]=v.w;
    }
    #pragma unroll
    for (int p=0; p<4; p++){
      int idx = p*256 + tid;
      int kq = idx & 15, col = idx >> 4;
      int j = cbase + col;
      const float* src = (wmode > 0)
          ? ((j < wmode) ? Bm + (size_t)j*2*K + c0 + kq*4
                         : Bm + (size_t)(j-wmode)*2*K + K + c0 + kq*4)
          : Bm + (size_t)j*K + c0 + kq*4;
      float4 v = {0.f,0.f,0.f,0.f};
      if (kq*4 + 4 <= cw) v = *(const float4*)src;
      else {
        if (kq*4+0 < cw) v.x = src[0];
        if (kq*4+1 < cw) v.y = src[1];
        if (kq*4+2 < cw) v.z = src[2];
        if (kq*4+3 < cw) v.w = src[3];
      }
      int swb = (kq & 14) << 1;
      int cs = col ^ swb;
      Bs[kq*4+0][cs]=v.x; Bs[kq*4+1][cs]=v.y; Bs[kq*4+2][cs]=v.z; Bs[kq*4+3][cs]=v.w;
    }
    __syncthreads();
    for (int k=0;k<cw;k++){
      int sw = ((k>>3)&7)<<2;
      float a0 = As[k][ty*2], a1 = As[k][ty*2+1];
      float b[4];
      *(float4*)b = *(const float4*)&Bs[k][(tx*4) ^ sw];
      acc[0][0]+=a0*b[0]; acc[0][1]+=a0*b[1]; acc[0][2]+=a0*b[2]; acc[0][3]+=a0*b[3];
      acc[1][0]+=a1*b[0]; acc[1][1]+=a1*b[1]; acc[1][2]+=a1*b[2]; acc[1][3]+=a1*b[3];
    }
    __syncthreads();
  }
  #pragma unroll
  for (int i=0;i<2;i++){
    int r = rbase + ty*2 + i;
    float o[4];
    #pragma unroll
    for (int j=0;j<4;j++){
      int cc = cbase + tx*4 + j;
      float v = acc[i][j];
      if (ep == 1) v = lrelu(p1[cc]*v*INV_SQRT1P + p2[cc]);
      o[j] = v;
    }
    *(float4*)(Om + (size_t)r*ldo + cbase + tx*4) = *(float4*)o;
  }
}

// ---------------- symmetric S = neg_d GEMM: 64x64 tile, 64 threads, 8x8/thread -------
// Triangular tiles tn >= tm (136 per batch); each block writes tile + transposed mirror.
// 16 KB LDS, grid 136 x chunkB = 1088 blocks -> ~4 blocks/CU; 8x8/thread is exactly
// LDS/VALU balanced (128 B/cyc <-> 128 FMA/cyc). XOR swizzle keeps phases <=2-way.
__global__ __launch_bounds__(64) void k_gsym(
    const float* __restrict__ Am, float* __restrict__ Om,
    int C, long long aBS, long long oBS, int b0, const float* __restrict__ xx)
{
  int bz = blockIdx.y;
  int batch = b0 + bz;
  const float* Ab = Am + (size_t)batch*aBS;
  float* Ob = Om + (size_t)bz*oBS;
  // decode triangular tile index: blockIdx.x in [0,136) -> (tm,tn), tm<=tn<16
  int rem = blockIdx.x; int tm = 0;
  while (rem >= 16 - tm){ rem -= 16 - tm; tm++; }
  int tn = tm + rem;
  __shared__ float As[32][64];
  __shared__ float Bs[32][64];
  int tid = threadIdx.x;
  int tx = tid & 7, ty = tid >> 3;
  int rbase = tm*64, cbase = tn*64;
  float acc[8][8];
  #pragma unroll
  for (int i=0;i<8;i++){
    #pragma unroll
    for (int j=0;j<8;j++) acc[i][j] = 0.f;
  }
  int kq  = tid & 7;          // k-quad: covers k = 4kq..4kq+3
  int swq = kq << 2;          // swizzle for those k
  int r0  = tid >> 3;         // 0..7
  for (int c0=0; c0<C; c0+=32){
    int cw = C - c0; if (cw > 32) cw = 32;
    // stage A: 64 rows x 32 k
    #pragma unroll
    for (int p=0; p<8; p++){
      int row = r0 + p*8;
      const float* src = Ab + (size_t)(rbase+row)*C + c0 + kq*4;
      float4 v = {0.f,0.f,0.f,0.f};
      if (kq*4 + 4 <= cw) v = *(const float4*)src;
      else {
        if (kq*4+0 < cw) v.x = src[0];
        if (kq*4+1 < cw) v.y = src[1];
        if (kq*4+2 < cw) v.z = src[2];
        if (kq*4+3 < cw) v.w = src[3];
      }
      int cs = row ^ swq;
      As[kq*4+0][cs]=v.x; As[kq*4+1][cs]=v.y; As[kq*4+2][cs]=v.z; As[kq*4+3][cs]=v.w;
    }
    // stage B: 64 cols x 32 k
    #pragma unroll
    for (int p=0; p<8; p++){
      int col = r0 + p*8;
      const float* src = Ab + (size_t)(cbase+col)*C + c0 + kq*4;
      float4 v = {0.f,0.f,0.f,0.f};
      if (kq*4 + 4 <= cw) v = *(const float4*)src;
      else {
        if (kq*4+0 < cw) v.x = src[0];
        if (kq*4+1 < cw) v.y = src[1];
        if (kq*4+2 < cw) v.z = src[2];
        if (kq*4+3 < cw) v.w = src[3];
      }
      int cs = col ^ swq;
      Bs[kq*4+0][cs]=v.x; Bs[kq*4+1][cs]=v.y; Bs[kq*4+2][cs]=v.z; Bs[kq*4+3][cs]=v.w;
    }
    __syncthreads();
    for (int k=0;k<cw;k++){
      int sw = ((k>>2)&7)<<2;
      float a[8], b[8];
      *(float4*)&a[0] = *(const float4*)&As[k][(ty*8) ^ sw];
      *(float4*)&a[4] = *(const float4*)&As[k][(ty*8+4) ^ sw];
      *(float4*)&b[0] = *(const float4*)&Bs[k][(tx*8) ^ sw];
      *(float4*)&b[4] = *(const float4*)&Bs[k][(tx*8+4) ^ sw];
      #pragma unroll
      for (int i=0;i<8;i++){
        #pragma unroll
        for (int j=0;j<8;j++) acc[i][j] += a[i]*b[j];
      }
    }
    __syncthreads();
  }
  const float* xxb = xx + ((size_t)batch << 10);
  float ov[8][8];
  #pragma unroll
  for (int i=0;i<8;i++){
    float xr = xxb[rbase + ty*8 + i];
    #pragma unroll
    for (int j=0;j<8;j++)
      ov[i][j] = 2.f*acc[i][j] - xr - xxb[cbase + tx*8 + j];
  }
  // normal store: rows rbase+ty*8+i, cols cbase+tx*8..+7
  #pragma unroll
  for (int i=0;i<8;i++){
    float* dst = Ob + (size_t)(rbase + ty*8 + i)*1024 + cbase + tx*8;
    *(float4*)&dst[0] = *(float4*)&ov[i][0];
    *(float4*)&dst[4] = *(float4*)&ov[i][4];
  }
  // mirror store: rows cbase+tx*8+j, cols rbase+ty*8..+7 (transpose; same values)
  #pragma unroll
  for (int j=0;j<8;j++){
    float lo[4] = {ov[0][j], ov[1][j], ov[2][j], ov[3][j]};
    float hi[4] = {ov[4][j], ov[5][j], ov[6][j], ov[7][j]};
    float* dst = Ob + (size_t)(cbase + tx*8 + j)*1024 + rbase + ty*8;
    *(float4*)dst       = *(float4*)lo;
    *(float4*)(dst + 4) = *(float4*)hi;
  }
}

// ---------------- top-20 of a 1024-length neg_d row (1 wave per row) ----------------
__global__ __launch_bounds__(64) void k_topk(const float* __restrict__ S,
      int* __restrict__ idx, int b0){
  int rl = blockIdx.x;
  int bz = rl >> 10; int n = rl & 1023;
  int b  = b0 + bz;
  int l  = threadIdx.x;
  const float* Srow = S + (size_t)rl*1024;
  float v[16];
  #pragma unroll
  for (int j=0;j<16;j++) v[j] = Srow[l + 64*j];
  int out_base = (((b<<10)+n))*20;

  float lmax = v[0];
  #pragma unroll
  for (int j=1;j<16;j++) lmax = fmaxf(lmax, v[j]);

  float sv = lmax;
  #pragma unroll
  for (int k=2; k<=64; k<<=1){
    #pragma unroll
    for (int j=k>>1; j>0; j>>=1){
      float o = __shfl_xor(sv, j, 64);
      bool a  = (l & k) == 0;
      bool bb = (l & j) == 0;
      sv = (a == bb) ? fminf(sv, o) : fmaxf(sv, o);
    }
  }
  float tau = __shfl(sv, 44, 64);   // 20th largest lane max

  int cnt = 0;
  #pragma unroll
  for (int j=0;j<16;j++) cnt += (v[j] >= tau) ? 1 : 0;
  int inc = cnt;
  #pragma unroll
  for (int off=1; off<64; off<<=1){
    int t = __shfl_up(inc, off, 64);
    inc += (l >= off) ? t : 0;
  }
  int Ns = __shfl(inc, 63, 64);

  __shared__ unsigned long long sl[128];

  if (Ns <= 128){
    sl[l] = 0ull; sl[64+l] = 0ull;
    __syncthreads();
    int slot = inc - cnt;
    #pragma unroll
    for (int j=0;j<16;j++){
      if (v[j] >= tau){
        unsigned int mv = __float_as_uint(v[j]);
        mv = (mv & 0x80000000u) ? ~mv : (mv | 0x80000000u);
        sl[slot] = ((unsigned long long)mv << 10) | (unsigned)(1023 - (l + 64*j));
        slot++;
      }
    }
    __syncthreads();
    unsigned long long c0 = sl[l], c1 = sl[64+l];
    for (int kk=0; kk<20; kk++){
      unsigned long long m = c0 > c1 ? c0 : c1;
      #pragma unroll
      for (int off=32; off>0; off>>=1){
        unsigned long long o = __shfl_xor(m, off, 64);
        m = o > m ? o : m;
      }
      c0 = (c0 == m) ? 0ull : c0;
      c1 = (c1 == m) ? 0ull : c1;
      if (l == 0) idx[out_base + kk] = 1023 - (int)(m & 1023ull);
    }
  } else {
    for (int kk=0; kk<20; kk++){
      float bv = NEGINIT; int bi = 0x3fffffff;
      #pragma unroll
      for (int j=0;j<16;j++){
        if (v[j] > bv){ bv = v[j]; bi = l + 64*j; }
      }
      #pragma unroll
      for (int off=32; off>0; off>>=1){
        float ov = __shfl_xor(bv, off, 64);
        int   oi = __shfl_xor(bi, off, 64);
        if (ov > bv || (ov == bv && oi < bi)){ bv = ov; bi = oi; }
      }
      int wl = bi & 63, wj = bi >> 6;
      #pragma unroll
      for (int j=0;j<16;j++)
        v[j] = (l == wl && j == wj) ? REMOVED : v[j];
      if (l == 0) idx[out_base + kk] = bi;
    }
  }
}

// ---------------- edge epilogue: gather Y1 at neighbors, +center, scale/bias/lrelu, max_k
__global__ void k_edge(const float* __restrict__ Y, const int* __restrict__ idx,
    const float* __restrict__ g, const float* __restrict__ bias,
    float* __restrict__ out, int O, int ldo, int ooff){
  int row = blockIdx.x; int o = threadIdx.x; int b = row >> 10;
  __shared__ int js[20];
  if (threadIdx.x < 20) js[threadIdx.x] = idx[row*20 + threadIdx.x];
  __syncthreads();
  int O2 = O*2;
  float y1c = Y[(size_t)row*O2 + o];
  float d   = Y[(size_t)row*O2 + O + o] - y1c;
  float sc  = g[o] * INV_SQRT1P;
  float bb  = bias[o];
  const float* Yb = Y + ((size_t)(b<<10))*O2;
  float best = -1e38f;
  #pragma unroll
  for (int k=0;k<20;k++){
    float f = sc * (Yb[(size_t)js[k]*O2 + o] + d) + bb;
    best = fmaxf(best, lrelu(f));
  }
  out[(size_t)row*ldo + ooff + o] = best;
}

// ---------------- attention ----------------
__global__ __launch_bounds__(1024) void k_mean(const float* __restrict__ emb, float* __restrict__ m){
  int b = blockIdx.x; int f = threadIdx.x & 127; int ny = threadIdx.x >> 7;
  const float* e = emb + ((size_t)(b<<10) + ny*128)*128 + f;
  float s = 0.f;
  for (int n=0;n<128;n++) s += e[n*128];
  __shared__ float red[8][128];
  red[ny][f] = s;
  __syncthreads();
  if (ny == 0){
    float t = 0.f;
    #pragma unroll
    for (int i=0;i<8;i++) t += red[i][f];
    m[b*128+f] = t * (1.0f/1024.0f);
  }
}

__global__ __launch_bounds__(128) void k_gc(const float* __restrict__ m, const float* __restrict__ att_w,
     float* __restrict__ gc){
  int b = blockIdx.x, g = threadIdx.x;
  __shared__ float mr[128];
  mr[g] = m[b*128+g];
  __syncthreads();
  float s = 0.f;
  for (int f=0; f<128; f++) s += mr[f]*att_w[f*128+g];
  gc[b*128+g] = tanhf(s);
}

__global__ __launch_bounds__(64) void k_sc(const float* __restrict__ emb, const float* __restrict__ gc,
     float* __restrict__ sc, float* __restrict__ attout){
  int row = blockIdx.x; int l = threadIdx.x; int b = row >> 10;
  const float* e  = emb + (size_t)row*128;
  const float* gb = gc + b*128;
  float p = e[l]*gb[l] + e[l+64]*gb[l+64];
  #pragma unroll
  for (int off=32; off>0; off>>=1) p += __shfl_xor(p, off, 64);
  if (l == 0){
    float s = 1.0f/(1.0f + expf(-p));
    sc[row] = s;
    attout[row] = s;
  }
}

__global__ __launch_bounds__(1024) void k_pool(const float* __restrict__ emb, const float* __restrict__ sc,
     float* __restrict__ ep){
  int b = blockIdx.x; int f = threadIdx.x & 127; int ny = threadIdx.x >> 7;
  const float* e  = emb + ((size_t)(b<<10) + ny*128)*128 + f;
  const float* sb = sc + (b<<10) + ny*128;
  float s = 0.f;
  for (int n=0;n<128;n++) s += e[n*128]*sb[n];
  __shared__ float red[8][128];
  red[ny][f] = s;
  __syncthreads();
  if (ny == 0){
    float t = 0.f;
    #pragma unroll
    for (int i=0;i<8;i++) t += red[i][f];
    ep[b*128+f] = t;
  }
}

// ---------------- tensor network scoring ----------------
__global__ __launch_bounds__(256) void k_tnet(const float* __restrict__ e1, const float* __restrict__ e2,
    const float* __restrict__ tn_w, const float* __restrict__ tn_wb, const float* __restrict__ tn_bias,
    float* __restrict__ tsout){
  int b = blockIdx.x; int t = threadIdx.x; int tt = t & 15; int fs = t >> 4;
  __shared__ float E1[128], E2[128], red[16][17];
  if (t < 128){ E1[t] = e1[b*128+t]; E2[t] = e2[b*128+t]; }
  __syncthreads();
  float acc = 0.f;
  for (int f = fs*8; f < fs*8+8; f++){
    const float* tw = tn_w + f*128*16 + tt;
    float partial = 0.f;
    for (int g=0; g<128; g++) partial += E2[g]*tw[g*16];
    acc += E1[f]*partial;
  }
  red[fs][tt] = acc;
  __syncthreads();
  if (t < 16){
    float s = 0.f;
    #pragma unroll
    for (int i=0;i<16;i++) s += red[i][t];
    float acc2 = 0.f;
    for (int c=0;c<128;c++) acc2 += tn_wb[t*256+c]*E1[c] + tn_wb[t*256+128+c]*E2[c];
    float v = s + acc2 + tn_bias[t];
    tsout[b*16+t] = v > 0.f ? v : 0.f;
  }
}

__global__ __launch_bounds__(128) void k_score2(const float* __restrict__ ts,
   const float* __restrict__ fc1_w, const float* __restrict__ fc1_b,
   const float* __restrict__ sc_w, const float* __restrict__ sc_b, float* __restrict__ out){
  int t = threadIdx.x; int b = t >> 4, i = t & 15;
  __shared__ float h2[8][17];
  float a = 0.f;
  #pragma unroll
  for (int k=0;k<16;k++) a += ts[b*16+k]*fc1_w[i*16+k];
  a += fc1_b[i];
  h2[b][i] = a > 0.f ? a : 0.f;
  __syncthreads();
  if (t < 8){
    float s = 0.f;
    #pragma unroll
    for (int k=0;k<16;k++) s += h2[t][k]*sc_w[k];
    s += sc_b[0];
    out[t] = 1.0f/(1.0f + expf(-s));
  }
}

extern "C" void kernel_launch(void* const* d_in, const int* in_sizes, int n_in,
                              void* d_out, int out_size, void* d_ws, size_t ws_size,
                              hipStream_t stream){
  const float* f1  = (const float*)d_in[0];
  const float* f2  = (const float*)d_in[1];
  const float* sw1 = (const float*)d_in[2];  const float* sg1 = (const float*)d_in[3];  const float* sb1 = (const float*)d_in[4];
  const float* fw1 = (const float*)d_in[5];  const float* fg1 = (const float*)d_in[6];  const float* fb1 = (const float*)d_in[7];
  const float* sw2 = (const float*)d_in[8];  const float* sg2 = (const float*)d_in[9];  const float* sb2 = (const float*)d_in[10];
  const float* fw2 = (const float*)d_in[11]; const float* fg2 = (const float*)d_in[12]; const float* fb2 = (const float*)d_in[13];
  const float* sw3 = (const float*)d_in[14]; const float* sg3 = (const float*)d_in[15]; const float* sb3 = (const float*)d_in[16];
  const float* fw3 = (const float*)d_in[17]; const float* fg3 = (const float*)d_in[18]; const float* fb3 = (const float*)d_in[19];
  const float* ew  = (const float*)d_in[20]; const float* eg  = (const float*)d_in[21]; const float* eb  = (const float*)d_in[22];
  const float* att_w   = (const float*)d_in[23];
  const float* tn_w    = (const float*)d_in[24];
  const float* tn_wb   = (const float*)d_in[25];
  const float* tn_bias = (const float*)d_in[26];
  const float* fc1_w   = (const float*)d_in[27];
  const float* fc1_b   = (const float*)d_in[28];
  const float* sc_w    = (const float*)d_in[29];
  const float* sc_b    = (const float*)d_in[30];

  float* W    = (float*)d_ws;
  float* T0   = W;                 // 1048576
  float* T1   = W + 1048576;       // 1048576
  float* X3S3 = W + 2097152;       // 2097152 (8192 x 256 concat)
  float* Y    = W + 4194304;       // 2097152 (8192 x <=256)
  float* emb1 = W + 6291456;       // 1048576
  float* emb2 = W + 7340032;       // 1048576
  float* xx   = W + 8388608;       // 8192
  float* mb   = W + 8396800;       // 1024
  float* gcb  = W + 8397824;       // 1024
  float* scb  = W + 8398848;       // 8192
  float* e1b  = W + 8407040;       // 1024
  float* e2b  = W + 8408064;       // 1024
  float* tsb  = W + 8409088;       // 128
  int*   idxb = (int*)(W + 8409216); // 163840 ints
  float* S    = W + 8573056;       // chunkB * 1048576

  size_t base = 8573056;
  int chunkB = 8;
  while (chunkB > 1 && (base + (size_t)chunkB*1048576)*sizeof(float) > ws_size) chunkB >>= 1;

  float* out = (float*)d_out;

  auto edge = [&](const float* xin, int C, int O,
                  const float* w, const float* g, const float* bb,
                  float* xout, int ldo, int ooff){
    k_xx<<<32, 256, 0, stream>>>(xin, xx, C);
    k_gthin<<<dim3(2*O/64, 256, 1), 256, 0, stream>>>(xin, w, Y, C, 2*O,
          O, nullptr, nullptr, 0);
    for (int b0=0; b0<8; b0+=chunkB){
      k_gsym<<<dim3(136, chunkB), 64, 0, stream>>>(xin, S, C,
            (long long)1024*C, 1048576ll, b0, xx);
      k_topk<<<1024*chunkB, 64, 0, stream>>>(S, idxb, b0);
    }
    k_edge<<<8192, O, 0, stream>>>(Y, idxb, g, bb, xout, O, ldo, ooff);
  };

  auto run_pass = [&](const float* feat,
                      const float* w1,const float* g1,const float* b1,
                      const float* w2,const float* g2,const float* b2,
                      const float* w3,const float* g3,const float* b3,
                      const float* v1,const float* h1,const float* c1,
                      const float* v2,const float* h2,const float* c2,
                      const float* v3,const float* h3,const float* c3,
                      float* emb, float* attout, float* epool){
    // xyz path
    k_extract<<<(8*3*1024+255)/256, 256, 0, stream>>>(feat, T0, 0, 3);
    edge(T0, 3,   64, w1, g1, b1, T1, 64, 0);
    edge(T1, 64,  64, w2, g2, b2, T0, 64, 0);
    edge(T0, 64, 128, w3, g3, b3, X3S3, 256, 0);     // x3 -> cols 0..127
    // sem path
    k_extract<<<(8*128*1024+255)/256, 256, 0, stream>>>(feat, T0, 3, 128);
    edge(T0, 128, 64, v1, h1, c1, T1, 64, 0);
    edge(T1, 64,  64, v2, h2, c2, T0, 64, 0);
    edge(T0, 64, 128, v3, h3, c3, X3S3, 256, 128);   // s3 -> cols 128..255
    // combine: emb = lrelu(eg * (X3S3 @ ew^T)/sqrt(1+eps) + eb)
    k_gthin<<<dim3(2, 256, 1), 256, 0, stream>>>(X3S3, ew, emb, 256, 128,
          0, eg, eb, 1);
    // attention
    k_mean<<<8, 1024, 0, stream>>>(emb, mb);
    k_gc<<<8, 128, 0, stream>>>(mb, att_w, gcb);
    k_sc<<<8192, 64, 0, stream>>>(emb, gcb, scb, attout);
    k_pool<<<8, 1024, 0, stream>>>(emb, scb, epool);
  };

  run_pass(f1, sw1,sg1,sb1, sw2,sg2,sb2, sw3,sg3,sb3,
               fw1,fg1,fb1, fw2,fg2,fb2, fw3,fg3,fb3,
               emb1, out + 8, e1b);
  run_pass(f2, sw1,sg1,sb1, sw2,sg2,sb2, sw3,sg3,sb3,
               fw1,fg1,fb1, fw2,fg2,fb2, fw3,fg3,fb3,
               emb2, out + 8 + 8192, e2b);

  k_tnet<<<8, 256, 0, stream>>>(e1b, e2b, tn_w, tn_wb, tn_bias, tsb);
  k_score2<<<1, 128, 0, stream>>>(tsb, fc1_w, fc1_b, sc_w, sc_b, out);
}

// Round 10
// 897.666 us; speedup vs baseline: 1.3474x; 1.3474x over previous
//
#include <hip/hip_runtime.h>
#include <math.h>

#define INV_SQRT1P 0.99999500003749968754f   // 1/sqrt(1+1e-5)
#define REMOVED  -2.0e38f
#define NEGINIT  -3.0e38f

static __device__ __forceinline__ float lrelu(float f){ return f >= 0.0f ? f : 0.2f*f; }

// ---------------- extract channels: feat (8,131,1024) -> out rows [boff*1024 ...) (N,Cout)
__global__ void k_extract(const float* __restrict__ f, float* __restrict__ out, int c0, int Cout, int boff){
  int i = blockIdx.x*256 + threadIdx.x;
  int total = 8*Cout*1024;
  if (i >= total) return;
  int n  = i & 1023;
  int bc = i >> 10;
  int c  = bc % Cout;
  int b  = bc / Cout;
  out[((size_t)(((b+boff)<<10)+n))*Cout + c] = f[((size_t)(b*131 + c0 + c) << 10) + n];
}

// ---------------- row sum of squares: x (16384,C) -> xx (16384) ----------------
__global__ void k_xx(const float* __restrict__ x, float* __restrict__ xx, int C){
  int r = blockIdx.x*256 + threadIdx.x;
  if (r >= 16384) return;
  const float* xr = x + (size_t)r*C;
  float s = 0.f;
  for (int c=0;c<C;c++) s += xr[c]*xr[c];
  xx[r] = s;
}

// ---------------- thin NT GEMM: 32 rows x 64 cols per block, 2x4/thread ----------------
// grid = (cols/64, 16384/32). wmode>0: B is (O,2K) conv weight remapped to (2O,K).
// ep==1: out = lrelu(p1[col]*acc/sqrt(1+eps) + p2[col])
__global__ __launch_bounds__(256) void k_gthin(
    const float* __restrict__ Am, const float* __restrict__ Bm, float* __restrict__ Om,
    int K, int ldo, int wmode, const float* __restrict__ p1, const float* __restrict__ p2, int ep)
{
  __shared__ float As[64][33];   // k-major, conflict-free scalar access
  __shared__ float Bs[64][68];   // k-major + XOR swizzle on col
  int tid = threadIdx.x;
  int tx = tid & 15, ty = tid >> 4;
  int rbase = blockIdx.y*32, cbase = blockIdx.x*64;
  float acc[2][4];
  #pragma unroll
  for (int i=0;i<2;i++){ acc[i][0]=0.f; acc[i][1]=0.f; acc[i][2]=0.f; acc[i][3]=0.f; }

  for (int c0=0; c0<K; c0+=64){
    int cw = K - c0; if (cw > 64) cw = 64;
    #pragma unroll
    for (int p=0; p<2; p++){
      int idx = p*256 + tid;
      int kq = idx & 15, row = idx >> 4;
      const float* src = Am + (size_t)(rbase+row)*K + c0 + kq*4;
      float4 v = {0.f,0.f,0.f,0.f};
      if (kq*4 + 4 <= cw) v = *(const float4*)src;
      else {
        if (kq*4+0 < cw) v.x = src[0];
        if (kq*4+1 < cw) v.y = src[1];
        if (kq*4+2 < cw) v.z = src[2];
        if (kq*4+3 < cw) v.w = src[3];
      }
      As[kq*4+0][row]=v.x; As[kq*4+1][row]=v.y; As[kq*4+2][row]=v.z; As[kq*4+3][row]=v.w;
    }
    #pragma unroll
    for (int p=0; p<4; p++){
      int idx = p*256 + tid;
      int kq = idx & 15, col = idx >> 4;
      int j = cbase + col;
      const float* src = (wmode > 0)
          ? ((j < wmode) ? Bm + (size_t)j*2*K + c0 + kq*4
                         : Bm + (size_t)(j-wmode)*2*K + K + c0 + kq*4)
          : Bm + (size_t)j*K + c0 + kq*4;
      float4 v = {0.f,0.f,0.f,0.f};
      if (kq*4 + 4 <= cw) v = *(const float4*)src;
      else {
        if (kq*4+0 < cw) v.x = src[0];
        if (kq*4+1 < cw) v.y = src[1];
        if (kq*4+2 < cw) v.z = src[2];
        if (kq*4+3 < cw) v.w = src[3];
      }
      int swb = (kq & 14) << 1;
      int cs = col ^ swb;
      Bs[kq*4+0][cs]=v.x; Bs[kq*4+1][cs]=v.y; Bs[kq*4+2][cs]=v.z; Bs[kq*4+3][cs]=v.w;
    }
    __syncthreads();
    for (int k=0;k<cw;k++){
      int sw = ((k>>3)&7)<<2;
      float a0 = As[k][ty*2], a1 = As[k][ty*2+1];
      float b[4];
      *(float4*)b = *(const float4*)&Bs[k][(tx*4) ^ sw];
      acc[0][0]+=a0*b[0]; acc[0][1]+=a0*b[1]; acc[0][2]+=a0*b[2]; acc[0][3]+=a0*b[3];
      acc[1][0]+=a1*b[0]; acc[1][1]+=a1*b[1]; acc[1][2]+=a1*b[2]; acc[1][3]+=a1*b[3];
    }
    __syncthreads();
  }
  #pragma unroll
  for (int i=0;i<2;i++){
    int r = rbase + ty*2 + i;
    float o[4];
    #pragma unroll
    for (int j=0;j<4;j++){
      int cc = cbase + tx*4 + j;
      float v = acc[i][j];
      if (ep == 1) v = lrelu(p1[cc]*v*INV_SQRT1P + p2[cc]);
      o[j] = v;
    }
    *(float4*)(Om + (size_t)r*ldo + cbase + tx*4) = *(float4*)o;
  }
}

// ---------------- symmetric S = neg_d GEMM: 128x64 tile, BK=32, 8x4/thread -----------
// (R8-proven shape.) Tiles tn >= 2*tm (72 of 128); each block writes tile + transposed
// mirror (S symmetric; overlap regions write identical values).
__global__ __launch_bounds__(256) void k_gsym(
    const float* __restrict__ Am, float* __restrict__ Om,
    int C, long long aBS, long long oBS, int b0, const float* __restrict__ xx)
{
  int bz = blockIdx.z;
  int batch = b0 + bz;
  const float* Ab = Am + (size_t)batch*aBS;
  float* Ob = Om + (size_t)bz*oBS;
  int rem = blockIdx.x; int tm = 0;
  while (rem >= 16 - 2*tm){ rem -= 16 - 2*tm; tm++; }
  int tn = 2*tm + rem;
  __shared__ float As[32][128];
  __shared__ float Bs[32][64];
  int tid = threadIdx.x;
  int tx = tid & 15, ty = tid >> 4;
  int rbase = tm*128, cbase = tn*64;
  float acc[8][4];
  #pragma unroll
  for (int i=0;i<8;i++){
    #pragma unroll
    for (int j=0;j<4;j++) acc[i][j] = 0.f;
  }
  int kq  = tid & 7;
  int swq = kq << 2;
  int r0  = tid >> 3;
  for (int c0=0; c0<C; c0+=32){
    int cw = C - c0; if (cw > 32) cw = 32;
    #pragma unroll
    for (int p=0; p<4; p++){
      int row = r0 + p*32;
      const float* src = Ab + (size_t)(rbase+row)*C + c0 + kq*4;
      float4 v = {0.f,0.f,0.f,0.f};
      if (kq*4 + 4 <= cw) v = *(const float4*)src;
      else {
        if (kq*4+0 < cw) v.x = src[0];
        if (kq*4+1 < cw) v.y = src[1];
        if (kq*4+2 < cw) v.z = src[2];
        if (kq*4+3 < cw) v.w = src[3];
      }
      int cs = row ^ swq;
      As[kq*4+0][cs]=v.x; As[kq*4+1][cs]=v.y; As[kq*4+2][cs]=v.z; As[kq*4+3][cs]=v.w;
    }
    #pragma unroll
    for (int p=0; p<2; p++){
      int col = r0 + p*32;
      const float* src = Ab + (size_t)(cbase+col)*C + c0 + kq*4;
      float4 v = {0.f,0.f,0.f,0.f};
      if (kq*4 + 4 <= cw) v = *(const float4*)src;
      else {
        if (kq*4+0 < cw) v.x = src[0];
        if (kq*4+1 < cw) v.y = src[1];
        if (kq*4+2 < cw) v.z = src[2];
        if (kq*4+3 < cw) v.w = src[3];
      }
      int cs = col ^ swq;
      Bs[kq*4+0][cs]=v.x; Bs[kq*4+1][cs]=v.y; Bs[kq*4+2][cs]=v.z; Bs[kq*4+3][cs]=v.w;
    }
    __syncthreads();
    for (int k=0;k<cw;k++){
      int sw = ((k>>2)&7)<<2;
      float a[8], b[4];
      *(float4*)&a[0] = *(const float4*)&As[k][(ty*8) ^ sw];
      *(float4*)&a[4] = *(const float4*)&As[k][(ty*8+4) ^ sw];
      *(float4*)&b[0] = *(const float4*)&Bs[k][(tx*4) ^ sw];
      #pragma unroll
      for (int i=0;i<8;i++){
        #pragma unroll
        for (int j=0;j<4;j++) acc[i][j] += a[i]*b[j];
      }
    }
    __syncthreads();
  }
  const float* xxb = xx + ((size_t)batch << 10);
  float ov[8][4];
  #pragma unroll
  for (int i=0;i<8;i++){
    float xr = xxb[rbase + ty*8 + i];
    #pragma unroll
    for (int j=0;j<4;j++)
      ov[i][j] = 2.f*acc[i][j] - xr - xxb[cbase + tx*4 + j];
  }
  #pragma unroll
  for (int i=0;i<8;i++){
    float o[4] = {ov[i][0], ov[i][1], ov[i][2], ov[i][3]};
    *(float4*)(Ob + (size_t)(rbase + ty*8 + i)*1024 + cbase + tx*4) = *(float4*)o;
  }
  #pragma unroll
  for (int j=0;j<4;j++){
    float lo[4] = {ov[0][j], ov[1][j], ov[2][j], ov[3][j]};
    float hi[4] = {ov[4][j], ov[5][j], ov[6][j], ov[7][j]};
    float* dst = Ob + (size_t)(cbase + tx*4 + j)*1024 + rbase + ty*8;
    *(float4*)dst       = *(float4*)lo;
    *(float4*)(dst + 4) = *(float4*)hi;
  }
}

// ---------------- top-20 of a 1024-length neg_d row (1 wave per row) ----------------
__global__ __launch_bounds__(64) void k_topk(const float* __restrict__ S,
      int* __restrict__ idx, int b0){
  int rl = blockIdx.x;
  int bz = rl >> 10; int n = rl & 1023;
  int b  = b0 + bz;
  int l  = threadIdx.x;
  const float* Srow = S + (size_t)rl*1024;
  float v[16];
  #pragma unroll
  for (int j=0;j<16;j++) v[j] = Srow[l + 64*j];
  int out_base = (((b<<10)+n))*20;

  float lmax = v[0];
  #pragma unroll
  for (int j=1;j<16;j++) lmax = fmaxf(lmax, v[j]);

  float sv = lmax;
  #pragma unroll
  for (int k=2; k<=64; k<<=1){
    #pragma unroll
    for (int j=k>>1; j>0; j>>=1){
      float o = __shfl_xor(sv, j, 64);
      bool a  = (l & k) == 0;
      bool bb = (l & j) == 0;
      sv = (a == bb) ? fminf(sv, o) : fmaxf(sv, o);
    }
  }
  float tau = __shfl(sv, 44, 64);   // 20th largest lane max

  int cnt = 0;
  #pragma unroll
  for (int j=0;j<16;j++) cnt += (v[j] >= tau) ? 1 : 0;
  int inc = cnt;
  #pragma unroll
  for (int off=1; off<64; off<<=1){
    int t = __shfl_up(inc, off, 64);
    inc += (l >= off) ? t : 0;
  }
  int Ns = __shfl(inc, 63, 64);

  __shared__ unsigned long long sl[128];

  if (Ns <= 128){
    sl[l] = 0ull; sl[64+l] = 0ull;
    __syncthreads();
    int slot = inc - cnt;
    #pragma unroll
    for (int j=0;j<16;j++){
      if (v[j] >= tau){
        unsigned int mv = __float_as_uint(v[j]);
        mv = (mv & 0x80000000u) ? ~mv : (mv | 0x80000000u);
        sl[slot] = ((unsigned long long)mv << 10) | (unsigned)(1023 - (l + 64*j));
        slot++;
      }
    }
    __syncthreads();
    unsigned long long c0 = sl[l], c1 = sl[64+l];
    for (int kk=0; kk<20; kk++){
      unsigned long long m = c0 > c1 ? c0 : c1;
      #pragma unroll
      for (int off=32; off>0; off>>=1){
        unsigned long long o = __shfl_xor(m, off, 64);
        m = o > m ? o : m;
      }
      c0 = (c0 == m) ? 0ull : c0;
      c1 = (c1 == m) ? 0ull : c1;
      if (l == 0) idx[out_base + kk] = 1023 - (int)(m & 1023ull);
    }
  } else {
    for (int kk=0; kk<20; kk++){
      float bv = NEGINIT; int bi = 0x3fffffff;
      #pragma unroll
      for (int j=0;j<16;j++){
        if (v[j] > bv){ bv = v[j]; bi = l + 64*j; }
      }
      #pragma unroll
      for (int off=32; off>0; off>>=1){
        float ov = __shfl_xor(bv, off, 64);
        int   oi = __shfl_xor(bi, off, 64);
        if (ov > bv || (ov == bv && oi < bi)){ bv = ov; bi = oi; }
      }
      int wl = bi & 63, wj = bi >> 6;
      #pragma unroll
      for (int j=0;j<16;j++)
        v[j] = (l == wl && j == wj) ? REMOVED : v[j];
      if (l == 0) idx[out_base + kk] = bi;
    }
  }
}

// ---------------- edge epilogue: gather Y1 at neighbors, +center, scale/bias/lrelu, max_k
__global__ void k_edge(const float* __restrict__ Y, const int* __restrict__ idx,
    const float* __restrict__ g, const float* __restrict__ bias,
    float* __restrict__ out, int O, int ldo, int ooff){
  int row = blockIdx.x; int o = threadIdx.x; int b = row >> 10;
  __shared__ int js[20];
  if (threadIdx.x < 20) js[threadIdx.x] = idx[row*20 + threadIdx.x];
  __syncthreads();
  int O2 = O*2;
  float y1c = Y[(size_t)row*O2 + o];
  float d   = Y[(size_t)row*O2 + O + o] - y1c;
  float sc  = g[o] * INV_SQRT1P;
  float bb  = bias[o];
  const float* Yb = Y + ((size_t)(b<<10))*O2;
  float best = -1e38f;
  #pragma unroll
  for (int k=0;k<20;k++){
    float f = sc * (Yb[(size_t)js[k]*O2 + o] + d) + bb;
    best = fmaxf(best, lrelu(f));
  }
  out[(size_t)row*ldo + ooff + o] = best;
}

// ---------------- attention (16 batches) ----------------
__global__ __launch_bounds__(1024) void k_mean(const float* __restrict__ emb, float* __restrict__ m){
  int b = blockIdx.x; int f = threadIdx.x & 127; int ny = threadIdx.x >> 7;
  const float* e = emb + ((size_t)(b<<10) + ny*128)*128 + f;
  float s = 0.f;
  for (int n=0;n<128;n++) s += e[n*128];
  __shared__ float red[8][128];
  red[ny][f] = s;
  __syncthreads();
  if (ny == 0){
    float t = 0.f;
    #pragma unroll
    for (int i=0;i<8;i++) t += red[i][f];
    m[b*128+f] = t * (1.0f/1024.0f);
  }
}

__global__ __launch_bounds__(128) void k_gc(const float* __restrict__ m, const float* __restrict__ att_w,
     float* __restrict__ gc){
  int b = blockIdx.x, g = threadIdx.x;
  __shared__ float mr[128];
  mr[g] = m[b*128+g];
  __syncthreads();
  float s = 0.f;
  for (int f=0; f<128; f++) s += mr[f]*att_w[f*128+g];
  gc[b*128+g] = tanhf(s);
}

__global__ __launch_bounds__(64) void k_sc(const float* __restrict__ emb, const float* __restrict__ gc,
     float* __restrict__ sc, float* __restrict__ attout){
  int row = blockIdx.x; int l = threadIdx.x; int b = row >> 10;
  const float* e  = emb + (size_t)row*128;
  const float* gb = gc + b*128;
  float p = e[l]*gb[l] + e[l+64]*gb[l+64];
  #pragma unroll
  for (int off=32; off>0; off>>=1) p += __shfl_xor(p, off, 64);
  if (l == 0){
    float s = 1.0f/(1.0f + expf(-p));
    sc[row] = s;
    attout[row] = s;
  }
}

__global__ __launch_bounds__(1024) void k_pool(const float* __restrict__ emb, const float* __restrict__ sc,
     float* __restrict__ ep){
  int b = blockIdx.x; int f = threadIdx.x & 127; int ny = threadIdx.x >> 7;
  const float* e  = emb + ((size_t)(b<<10) + ny*128)*128 + f;
  const float* sb = sc + (b<<10) + ny*128;
  float s = 0.f;
  for (int n=0;n<128;n++) s += e[n*128]*sb[n];
  __shared__ float red[8][128];
  red[ny][f] = s;
  __syncthreads();
  if (ny == 0){
    float t = 0.f;
    #pragma unroll
    for (int i=0;i<8;i++) t += red[i][f];
    ep[b*128+f] = t;
  }
}

// ---------------- tensor network scoring ----------------
__global__ __launch_bounds__(256) void k_tnet(const float* __restrict__ e1, const float* __restrict__ e2,
    const float* __restrict__ tn_w, const float* __restrict__ tn_wb, const float* __restrict__ tn_bias,
    float* __restrict__ tsout){
  int b = blockIdx.x; int t = threadIdx.x; int tt = t & 15; int fs = t >> 4;
  __shared__ float E1[128], E2[128], red[16][17];
  if (t < 128){ E1[t] = e1[b*128+t]; E2[t] = e2[b*128+t]; }
  __syncthreads();
  float acc = 0.f;
  for (int f = fs*8; f < fs*8+8; f++){
    const float* tw = tn_w + f*128*16 + tt;
    float partial = 0.f;
    for (int g=0; g<128; g++) partial += E2[g]*tw[g*16];
    acc += E1[f]*partial;
  }
  red[fs][tt] = acc;
  __syncthreads();
  if (t < 16){
    float s = 0.f;
    #pragma unroll
    for (int i=0;i<16;i++) s += red[i][t];
    float acc2 = 0.f;
    for (int c=0;c<128;c++) acc2 += tn_wb[t*256+c]*E1[c] + tn_wb[t*256+128+c]*E2[c];
    float v = s + acc2 + tn_bias[t];
    tsout[b*16+t] = v > 0.f ? v : 0.f;
  }
}

__global__ __launch_bounds__(128) void k_score2(const float* __restrict__ ts,
   const float* __restrict__ fc1_w, const float* __restrict__ fc1_b,
   const float* __restrict__ sc_w, const float* __restrict__ sc_b, float* __restrict__ out){
  int t = threadIdx.x; int b = t >> 4, i = t & 15;
  __shared__ float h2[8][17];
  float a = 0.f;
  #pragma unroll
  for (int k=0;k<16;k++) a += ts[b*16+k]*fc1_w[i*16+k];
  a += fc1_b[i];
  h2[b][i] = a > 0.f ? a : 0.f;
  __syncthreads();
  if (t < 8){
    float s = 0.f;
    #pragma unroll
    for (int k=0;k<16;k++) s += h2[t][k]*sc_w[k];
    s += sc_b[0];
    out[t] = 1.0f/(1.0f + expf(-s));
  }
}

extern "C" void kernel_launch(void* const* d_in, const int* in_sizes, int n_in,
                              void* d_out, int out_size, void* d_ws, size_t ws_size,
                              hipStream_t stream){
  const float* f1  = (const float*)d_in[0];
  const float* f2  = (const float*)d_in[1];
  const float* sw1 = (const float*)d_in[2];  const float* sg1 = (const float*)d_in[3];  const float* sb1 = (const float*)d_in[4];
  const float* fw1 = (const float*)d_in[5];  const float* fg1 = (const float*)d_in[6];  const float* fb1 = (const float*)d_in[7];
  const float* sw2 = (const float*)d_in[8];  const float* sg2 = (const float*)d_in[9];  const float* sb2 = (const float*)d_in[10];
  const float* fw2 = (const float*)d_in[11]; const float* fg2 = (const float*)d_in[12]; const float* fb2 = (const float*)d_in[13];
  const float* sw3 = (const float*)d_in[14]; const float* sg3 = (const float*)d_in[15]; const float* sb3 = (const float*)d_in[16];
  const float* fw3 = (const float*)d_in[17]; const float* fg3 = (const float*)d_in[18]; const float* fb3 = (const float*)d_in[19];
  const float* ew  = (const float*)d_in[20]; const float* eg  = (const float*)d_in[21]; const float* eb  = (const float*)d_in[22];
  const float* att_w   = (const float*)d_in[23];
  const float* tn_w    = (const float*)d_in[24];
  const float* tn_wb   = (const float*)d_in[25];
  const float* tn_bias = (const float*)d_in[26];
  const float* fc1_w   = (const float*)d_in[27];
  const float* fc1_b   = (const float*)d_in[28];
  const float* sc_w    = (const float*)d_in[29];
  const float* sc_b    = (const float*)d_in[30];

  float* W    = (float*)d_ws;
  // 16-batch layout (both passes fused). ws_size ~256 MiB (observed via harness
  // re-poison fill of 268 MB); total footprint ~110 MB at full chunk.
  float* T0   = W;                  // 2,097,152  (16384 x <=128)
  float* T1   = W + 2097152;        // 2,097,152  (16384 x <=64 used)
  float* X3S3 = W + 4194304;        // 4,194,304  (16384 x 256)
  float* EMB  = W + 8388608;        // 2,097,152  (16384 x 128)
  float* xx   = W + 10485760;       // 16384
  float* mb   = W + 10502144;       // 2048
  float* gcb  = W + 10504192;       // 2048
  float* scb  = W + 10506240;       // 16384
  float* ep   = W + 10522624;       // 2048 (pass1: 0..1023, pass2: 1024..2047)
  float* tsb  = W + 10524672;       // 128
  int*   idxb = (int*)(W + 10524800); // 327680 ints (16384 x 20)
  float* REG  = W + 10852480;       // shared region: S (cB x 1M) / Y (<= 4M)

  size_t ws_floats = ws_size / 4;
  int cB = 16;
  while (cB > 1){
    size_t reg = (size_t)cB * 1048576; if (reg < 4194304) reg = 4194304;
    if (10852480 + reg <= ws_floats) break;
    cB--;
  }

  float* out = (float*)d_out;

  auto edge = [&](const float* xin, int C, int O,
                  const float* w, const float* g, const float* bb,
                  float* xout, int ldo, int ooff){
    k_xx<<<64, 256, 0, stream>>>(xin, xx, C);
    for (int b0=0; b0<16; b0+=cB){
      int nb = 16 - b0; if (nb > cB) nb = cB;
      k_gsym<<<dim3(72, 1, nb), 256, 0, stream>>>(xin, REG, C,
            (long long)1024*C, 1048576ll, b0, xx);
      k_topk<<<1024*nb, 64, 0, stream>>>(REG, idxb, b0);
    }
    // Y-GEMM after the top-k loop so Y can reuse the S region
    k_gthin<<<dim3(2*O/64, 512, 1), 256, 0, stream>>>(xin, w, REG, C, 2*O,
          O, nullptr, nullptr, 0);
    k_edge<<<16384, O, 0, stream>>>(REG, idxb, g, bb, xout, O, ldo, ooff);
  };

  // xyz path (both point clouds as batches 0-7 / 8-15)
  k_extract<<<(8*3*1024+255)/256, 256, 0, stream>>>(f1, T0, 0, 3, 0);
  k_extract<<<(8*3*1024+255)/256, 256, 0, stream>>>(f2, T0, 0, 3, 8);
  edge(T0, 3,   64, sw1, sg1, sb1, T1, 64, 0);
  edge(T1, 64,  64, sw2, sg2, sb2, T0, 64, 0);
  edge(T0, 64, 128, sw3, sg3, sb3, X3S3, 256, 0);    // x3 -> cols 0..127
  // sem path
  k_extract<<<(8*128*1024+255)/256, 256, 0, stream>>>(f1, T0, 3, 128, 0);
  k_extract<<<(8*128*1024+255)/256, 256, 0, stream>>>(f2, T0, 3, 128, 8);
  edge(T0, 128, 64, fw1, fg1, fb1, T1, 64, 0);
  edge(T1, 64,  64, fw2, fg2, fb2, T0, 64, 0);
  edge(T0, 64, 128, fw3, fg3, fb3, X3S3, 256, 128);  // s3 -> cols 128..255
  // combine: emb = lrelu(eg * (X3S3 @ ew^T)/sqrt(1+eps) + eb)
  k_gthin<<<dim3(2, 512, 1), 256, 0, stream>>>(X3S3, ew, EMB, 256, 128,
        0, eg, eb, 1);
  // attention over all 16 batches; attout rows = att1 (b<8) then att2 — matches out layout
  k_mean<<<16, 1024, 0, stream>>>(EMB, mb);
  k_gc<<<16, 128, 0, stream>>>(mb, att_w, gcb);
  k_sc<<<16384, 64, 0, stream>>>(EMB, gcb, scb, out + 8);
  k_pool<<<16, 1024, 0, stream>>>(EMB, scb, ep);

  k_tnet<<<8, 256, 0, stream>>>(ep, ep + 1024, tn_w, tn_wb, tn_bias, tsb);
  k_score2<<<1, 128, 0, stream>>>(tsb, fc1_w, fc1_b, sc_w, sc_b, out);
}

// Round 11
// 694.586 us; speedup vs baseline: 1.7414x; 1.2924x over previous
//
#include <hip/hip_runtime.h>
#include <math.h>

#define INV_SQRT1P 0.99999500003749968754f   // 1/sqrt(1+1e-5)
#define REMOVED  -2.0e38f
#define NEGINIT  -3.0e38f

static __device__ __forceinline__ float lrelu(float f){ return f >= 0.0f ? f : 0.2f*f; }

// ---------------- extract channels: feat (8,131,1024) -> out rows [boff*1024 ...) (N,Cout)
__global__ void k_extract(const float* __restrict__ f, float* __restrict__ out, int c0, int Cout, int boff){
  int i = blockIdx.x*256 + threadIdx.x;
  int total = 8*Cout*1024;
  if (i >= total) return;
  int n  = i & 1023;
  int bc = i >> 10;
  int c  = bc % Cout;
  int b  = bc / Cout;
  out[((size_t)(((b+boff)<<10)+n))*Cout + c] = f[((size_t)(b*131 + c0 + c) << 10) + n];
}

// ---------------- row sum of squares: x (16384,C) -> xx (16384) ----------------
__global__ void k_xx(const float* __restrict__ x, float* __restrict__ xx, int C){
  int r = blockIdx.x*256 + threadIdx.x;
  if (r >= 16384) return;
  const float* xr = x + (size_t)r*C;
  float s = 0.f;
  for (int c=0;c<C;c++) s += xr[c]*xr[c];
  xx[r] = s;
}

// ---------------- thin NT GEMM: 32 rows x 64 cols per block, 2x4/thread ----------------
__global__ __launch_bounds__(256) void k_gthin(
    const float* __restrict__ Am, const float* __restrict__ Bm, float* __restrict__ Om,
    int K, int ldo, int wmode, const float* __restrict__ p1, const float* __restrict__ p2, int ep)
{
  __shared__ float As[64][33];   // k-major, conflict-free scalar access
  __shared__ float Bs[64][68];   // k-major + XOR swizzle on col
  int tid = threadIdx.x;
  int tx = tid & 15, ty = tid >> 4;
  int rbase = blockIdx.y*32, cbase = blockIdx.x*64;
  float acc[2][4];
  #pragma unroll
  for (int i=0;i<2;i++){ acc[i][0]=0.f; acc[i][1]=0.f; acc[i][2]=0.f; acc[i][3]=0.f; }

  for (int c0=0; c0<K; c0+=64){
    int cw = K - c0; if (cw > 64) cw = 64;
    #pragma unroll
    for (int p=0; p<2; p++){
      int idx = p*256 + tid;
      int kq = idx & 15, row = idx >> 4;
      const float* src = Am + (size_t)(rbase+row)*K + c0 + kq*4;
      float4 v = {0.f,0.f,0.f,0.f};
      if (kq*4 + 4 <= cw) v = *(const float4*)src;
      else {
        if (kq*4+0 < cw) v.x = src[0];
        if (kq*4+1 < cw) v.y = src[1];
        if (kq*4+2 < cw) v.z = src[2];
        if (kq*4+3 < cw) v.w = src[3];
      }
      As[kq*4+0][row]=v.x; As[kq*4+1][row]=v.y; As[kq*4+2][row]=v.z; As[kq*4+3][row]=v.w;
    }
    #pragma unroll
    for (int p=0; p<4; p++){
      int idx = p*256 + tid;
      int kq = idx & 15, col = idx >> 4;
      int j = cbase + col;
      const float* src = (wmode > 0)
          ? ((j < wmode) ? Bm + (size_t)j*2*K + c0 + kq*4
                         : Bm + (size_t)(j-wmode)*2*K + K + c0 + kq*4)
          : Bm + (size_t)j*K + c0 + kq*4;
      float4 v = {0.f,0.f,0.f,0.f};
      if (kq*4 + 4 <= cw) v = *(const float4*)src;
      else {
        if (kq*4+0 < cw) v.x = src[0];
        if (kq*4+1 < cw) v.y = src[1];
        if (kq*4+2 < cw) v.z = src[2];
        if (kq*4+3 < cw) v.w = src[3];
      }
      int swb = (kq & 14) << 1;
      int cs = col ^ swb;
      Bs[kq*4+0][cs]=v.x; Bs[kq*4+1][cs]=v.y; Bs[kq*4+2][cs]=v.z; Bs[kq*4+3][cs]=v.w;
    }
    __syncthreads();
    for (int k=0;k<cw;k++){
      int sw = ((k>>3)&7)<<2;
      float a0 = As[k][ty*2], a1 = As[k][ty*2+1];
      float b[4];
      *(float4*)b = *(const float4*)&Bs[k][(tx*4) ^ sw];
      acc[0][0]+=a0*b[0]; acc[0][1]+=a0*b[1]; acc[0][2]+=a0*b[2]; acc[0][3]+=a0*b[3];
      acc[1][0]+=a1*b[0]; acc[1][1]+=a1*b[1]; acc[1][2]+=a1*b[2]; acc[1][3]+=a1*b[3];
    }
    __syncthreads();
  }
  #pragma unroll
  for (int i=0;i<2;i++){
    int r = rbase + ty*2 + i;
    float o[4];
    #pragma unroll
    for (int j=0;j<4;j++){
      int cc = cbase + tx*4 + j;
      float v = acc[i][j];
      if (ep == 1) v = lrelu(p1[cc]*v*INV_SQRT1P + p2[cc]);
      o[j] = v;
    }
    *(float4*)(Om + (size_t)r*ldo + cbase + tx*4) = *(float4*)o;
  }
}

// ---------------- symmetric S = neg_d GEMM: 128x64 tile, BK=32, 8x4/thread -----------
__global__ __launch_bounds__(256) void k_gsym(
    const float* __restrict__ Am, float* __restrict__ Om,
    int C, long long aBS, long long oBS, int b0, const float* __restrict__ xx)
{
  int bz = blockIdx.z;
  int batch = b0 + bz;
  const float* Ab = Am + (size_t)batch*aBS;
  float* Ob = Om + (size_t)bz*oBS;
  int rem = blockIdx.x; int tm = 0;
  while (rem >= 16 - 2*tm){ rem -= 16 - 2*tm; tm++; }
  int tn = 2*tm + rem;
  __shared__ float As[32][128];
  __shared__ float Bs[32][64];
  int tid = threadIdx.x;
  int tx = tid & 15, ty = tid >> 4;
  int rbase = tm*128, cbase = tn*64;
  float acc[8][4];
  #pragma unroll
  for (int i=0;i<8;i++){
    #pragma unroll
    for (int j=0;j<4;j++) acc[i][j] = 0.f;
  }
  int kq  = tid & 7;
  int swq = kq << 2;
  int r0  = tid >> 3;
  for (int c0=0; c0<C; c0+=32){
    int cw = C - c0; if (cw > 32) cw = 32;
    #pragma unroll
    for (int p=0; p<4; p++){
      int row = r0 + p*32;
      const float* src = Ab + (size_t)(rbase+row)*C + c0 + kq*4;
      float4 v = {0.f,0.f,0.f,0.f};
      if (kq*4 + 4 <= cw) v = *(const float4*)src;
      else {
        if (kq*4+0 < cw) v.x = src[0];
        if (kq*4+1 < cw) v.y = src[1];
        if (kq*4+2 < cw) v.z = src[2];
        if (kq*4+3 < cw) v.w = src[3];
      }
      int cs = row ^ swq;
      As[kq*4+0][cs]=v.x; As[kq*4+1][cs]=v.y; As[kq*4+2][cs]=v.z; As[kq*4+3][cs]=v.w;
    }
    #pragma unroll
    for (int p=0; p<2; p++){
      int col = r0 + p*32;
      const float* src = Ab + (size_t)(cbase+col)*C + c0 + kq*4;
      float4 v = {0.f,0.f,0.f,0.f};
      if (kq*4 + 4 <= cw) v = *(const float4*)src;
      else {
        if (kq*4+0 < cw) v.x = src[0];
        if (kq*4+1 < cw) v.y = src[1];
        if (kq*4+2 < cw) v.z = src[2];
        if (kq*4+3 < cw) v.w = src[3];
      }
      int cs = col ^ swq;
      Bs[kq*4+0][cs]=v.x; Bs[kq*4+1][cs]=v.y; Bs[kq*4+2][cs]=v.z; Bs[kq*4+3][cs]=v.w;
    }
    __syncthreads();
    for (int k=0;k<cw;k++){
      int sw = ((k>>2)&7)<<2;
      float a[8], b[4];
      *(float4*)&a[0] = *(const float4*)&As[k][(ty*8) ^ sw];
      *(float4*)&a[4] = *(const float4*)&As[k][(ty*8+4) ^ sw];
      *(float4*)&b[0] = *(const float4*)&Bs[k][(tx*4) ^ sw];
      #pragma unroll
      for (int i=0;i<8;i++){
        #pragma unroll
        for (int j=0;j<4;j++) acc[i][j] += a[i]*b[j];
      }
    }
    __syncthreads();
  }
  const float* xxb = xx + ((size_t)batch << 10);
  float ov[8][4];
  #pragma unroll
  for (int i=0;i<8;i++){
    float xr = xxb[rbase + ty*8 + i];
    #pragma unroll
    for (int j=0;j<4;j++)
      ov[i][j] = 2.f*acc[i][j] - xr - xxb[cbase + tx*4 + j];
  }
  #pragma unroll
  for (int i=0;i<8;i++){
    float o[4] = {ov[i][0], ov[i][1], ov[i][2], ov[i][3]};
    *(float4*)(Ob + (size_t)(rbase + ty*8 + i)*1024 + cbase + tx*4) = *(float4*)o;
  }
  #pragma unroll
  for (int j=0;j<4;j++){
    float lo[4] = {ov[0][j], ov[1][j], ov[2][j], ov[3][j]};
    float hi[4] = {ov[4][j], ov[5][j], ov[6][j], ov[7][j]};
    float* dst = Ob + (size_t)(cbase + tx*4 + j)*1024 + rbase + ty*8;
    *(float4*)dst       = *(float4*)lo;
    *(float4*)(dst + 4) = *(float4*)hi;
  }
}

// ---------------- top-20 of a 1024-length neg_d row (1 wave per row) ----------------
// tau = 20th-largest lane-max (exact prefilter, >=20 survivors guaranteed).
// Compact survivors to LDS as u64 keys (monotone_f32<<10 | (1023-m)); then:
//   Ns<=64 : one 21-step descending bitonic sort of 64 keys -> lanes 0..19 write.
//   Ns<=128: 20-round extract-max (rare)
//   else   : full rescan fallback (degenerate)
__global__ __launch_bounds__(64) void k_topk(const float* __restrict__ S,
      int* __restrict__ idx, int b0){
  int rl = blockIdx.x;
  int bz = rl >> 10; int n = rl & 1023;
  int b  = b0 + bz;
  int l  = threadIdx.x;
  const float4* Srow = (const float4*)(S + (size_t)rl*1024);
  float4 q[4];
  #pragma unroll
  for (int j=0;j<4;j++) q[j] = Srow[l + 64*j];   // covers m = 4*l + 256*j + {0..3}
  int out_base = (((b<<10)+n))*20;

  // per-lane max of 16
  float lmax = fmaxf(fmaxf(fmaxf(q[0].x,q[0].y),fmaxf(q[0].z,q[0].w)),
               fmaxf(fmaxf(fmaxf(q[1].x,q[1].y),fmaxf(q[1].z,q[1].w)),
               fmaxf(fmaxf(fmaxf(q[2].x,q[2].y),fmaxf(q[2].z,q[2].w)),
                     fmaxf(fmaxf(q[3].x,q[3].y),fmaxf(q[3].z,q[3].w)))));

  // ascending bitonic sort of 64 lane maxima -> tau at lane 44 (20th largest)
  float sv = lmax;
  #pragma unroll
  for (int k=2; k<=64; k<<=1){
    #pragma unroll
    for (int j=k>>1; j>0; j>>=1){
      float o = __shfl_xor(sv, j, 64);
      bool a  = (l & k) == 0;
      bool bb = (l & j) == 0;
      sv = (a == bb) ? fminf(sv, o) : fmaxf(sv, o);
    }
  }
  float tau = __shfl(sv, 44, 64);

  // count + exclusive scan
  float vv[16] = {q[0].x,q[0].y,q[0].z,q[0].w, q[1].x,q[1].y,q[1].z,q[1].w,
                  q[2].x,q[2].y,q[2].z,q[2].w, q[3].x,q[3].y,q[3].z,q[3].w};
  int cnt = 0;
  #pragma unroll
  for (int j=0;j<16;j++) cnt += (vv[j] >= tau) ? 1 : 0;
  int inc = cnt;
  #pragma unroll
  for (int off=1; off<64; off<<=1){
    int t = __shfl_up(inc, off, 64);
    inc += (l >= off) ? t : 0;
  }
  int Ns = __shfl(inc, 63, 64);

  __shared__ unsigned long long sl[128];

  if (Ns <= 128){
    sl[l] = 0ull; sl[64+l] = 0ull;
    __syncthreads();
    int slot = inc - cnt;
    #pragma unroll
    for (int j=0;j<16;j++){
      if (vv[j] >= tau){
        int m = 4*l + 64*(j & ~3) + (j & 3);   // j = 4*jj+qq -> m = 4l + 256*jj + qq
        unsigned int mv = __float_as_uint(vv[j]);
        mv = (mv & 0x80000000u) ? ~mv : (mv | 0x80000000u);
        sl[slot] = ((unsigned long long)mv << 10) | (unsigned)(1023 - m);
        slot++;
      }
    }
    __syncthreads();
    if (Ns <= 64){
      // descending bitonic sort of the (padded) 64 candidate keys
      unsigned long long key = sl[l];
      #pragma unroll
      for (int k=2; k<=64; k<<=1){
        #pragma unroll
        for (int j=k>>1; j>0; j>>=1){
          unsigned long long o = __shfl_xor(key, j, 64);
          bool a  = (l & k) == 0;
          bool bb = (l & j) == 0;
          unsigned long long mx = key > o ? key : o;
          unsigned long long mn = key > o ? o : key;
          key = (a == bb) ? mx : mn;     // descending
        }
      }
      if (l < 20) idx[out_base + l] = 1023 - (int)(key & 1023ull);
    } else {
      unsigned long long c0 = sl[l], c1 = sl[64+l];
      for (int kk=0; kk<20; kk++){
        unsigned long long m = c0 > c1 ? c0 : c1;
        #pragma unroll
        for (int off=32; off>0; off>>=1){
          unsigned long long o = __shfl_xor(m, off, 64);
          m = o > m ? o : m;
        }
        c0 = (c0 == m) ? 0ull : c0;
        c1 = (c1 == m) ? 0ull : c1;
        if (l == 0) idx[out_base + kk] = 1023 - (int)(m & 1023ull);
      }
    }
  } else {
    // degenerate fallback: exact 20-round extract-max over raw values
    for (int kk=0; kk<20; kk++){
      float bv = NEGINIT; int bi = 0x3fffffff;
      #pragma unroll
      for (int j=0;j<16;j++){
        int m = 4*l + 64*(j & ~3) + (j & 3);
        if (vv[j] > bv || (vv[j] == bv && m < bi)){ bv = vv[j]; bi = m; }
      }
      #pragma unroll
      for (int off=32; off>0; off>>=1){
        float ov = __shfl_xor(bv, off, 64);
        int   oi = __shfl_xor(bi, off, 64);
        if (ov > bv || (ov == bv && oi < bi)){ bv = ov; bi = oi; }
      }
      #pragma unroll
      for (int j=0;j<16;j++){
        int m = 4*l + 64*(j & ~3) + (j & 3);
        vv[j] = (m == bi) ? REMOVED : vv[j];
      }
      if (l == 0) idx[out_base + kk] = bi;
    }
  }
}

// ---------------- edge epilogue: gather Y1 at neighbors, +center, scale/bias/lrelu, max_k
__global__ void k_edge(const float* __restrict__ Y, const int* __restrict__ idx,
    const float* __restrict__ g, const float* __restrict__ bias,
    float* __restrict__ out, int O, int ldo, int ooff){
  int row = blockIdx.x; int o = threadIdx.x; int b = row >> 10;
  __shared__ int js[20];
  if (threadIdx.x < 20) js[threadIdx.x] = idx[row*20 + threadIdx.x];
  __syncthreads();
  int O2 = O*2;
  float y1c = Y[(size_t)row*O2 + o];
  float d   = Y[(size_t)row*O2 + O + o] - y1c;
  float sc  = g[o] * INV_SQRT1P;
  float bb  = bias[o];
  const float* Yb = Y + ((size_t)(b<<10))*O2;
  float best = -1e38f;
  #pragma unroll
  for (int k=0;k<20;k++){
    float f = sc * (Yb[(size_t)js[k]*O2 + o] + d) + bb;
    best = fmaxf(best, lrelu(f));
  }
  out[(size_t)row*ldo + ooff + o] = best;
}

// ---------------- attention (16 batches) ----------------
__global__ __launch_bounds__(1024) void k_mean(const float* __restrict__ emb, float* __restrict__ m){
  int b = blockIdx.x; int f = threadIdx.x & 127; int ny = threadIdx.x >> 7;
  const float* e = emb + ((size_t)(b<<10) + ny*128)*128 + f;
  float s = 0.f;
  for (int n=0;n<128;n++) s += e[n*128];
  __shared__ float red[8][128];
  red[ny][f] = s;
  __syncthreads();
  if (ny == 0){
    float t = 0.f;
    #pragma unroll
    for (int i=0;i<8;i++) t += red[i][f];
    m[b*128+f] = t * (1.0f/1024.0f);
  }
}

__global__ __launch_bounds__(128) void k_gc(const float* __restrict__ m, const float* __restrict__ att_w,
     float* __restrict__ gc){
  int b = blockIdx.x, g = threadIdx.x;
  __shared__ float mr[128];
  mr[g] = m[b*128+g];
  __syncthreads();
  float s = 0.f;
  for (int f=0; f<128; f++) s += mr[f]*att_w[f*128+g];
  gc[b*128+g] = tanhf(s);
}

__global__ __launch_bounds__(64) void k_sc(const float* __restrict__ emb, const float* __restrict__ gc,
     float* __restrict__ sc, float* __restrict__ attout){
  int row = blockIdx.x; int l = threadIdx.x; int b = row >> 10;
  const float* e  = emb + (size_t)row*128;
  const float* gb = gc + b*128;
  float p = e[l]*gb[l] + e[l+64]*gb[l+64];
  #pragma unroll
  for (int off=32; off>0; off>>=1) p += __shfl_xor(p, off, 64);
  if (l == 0){
    float s = 1.0f/(1.0f + expf(-p));
    sc[row] = s;
    attout[row] = s;
  }
}

__global__ __launch_bounds__(1024) void k_pool(const float* __restrict__ emb, const float* __restrict__ sc,
     float* __restrict__ ep){
  int b = blockIdx.x; int f = threadIdx.x & 127; int ny = threadIdx.x >> 7;
  const float* e  = emb + ((size_t)(b<<10) + ny*128)*128 + f;
  const float* sb = sc + (b<<10) + ny*128;
  float s = 0.f;
  for (int n=0;n<128;n++) s += e[n*128]*sb[n];
  __shared__ float red[8][128];
  red[ny][f] = s;
  __syncthreads();
  if (ny == 0){
    float t = 0.f;
    #pragma unroll
    for (int i=0;i<8;i++) t += red[i][f];
    ep[b*128+f] = t;
  }
}

// ---------------- tensor network scoring ----------------
__global__ __launch_bounds__(256) void k_tnet(const float* __restrict__ e1, const float* __restrict__ e2,
    const float* __restrict__ tn_w, const float* __restrict__ tn_wb, const float* __restrict__ tn_bias,
    float* __restrict__ tsout){
  int b = blockIdx.x; int t = threadIdx.x; int tt = t & 15; int fs = t >> 4;
  __shared__ float E1[128], E2[128], red[16][17];
  if (t < 128){ E1[t] = e1[b*128+t]; E2[t] = e2[b*128+t]; }
  __syncthreads();
  float acc = 0.f;
  for (int f = fs*8; f < fs*8+8; f++){
    const float* tw = tn_w + f*128*16 + tt;
    float partial = 0.f;
    for (int g=0; g<128; g++) partial += E2[g]*tw[g*16];
    acc += E1[f]*partial;
  }
  red[fs][tt] = acc;
  __syncthreads();
  if (t < 16){
    float s = 0.f;
    #pragma unroll
    for (int i=0;i<16;i++) s += red[i][t];
    float acc2 = 0.f;
    for (int c=0;c<128;c++) acc2 += tn_wb[t*256+c]*E1[c] + tn_wb[t*256+128+c]*E2[c];
    float v = s + acc2 + tn_bias[t];
    tsout[b*16+t] = v > 0.f ? v : 0.f;
  }
}

__global__ __launch_bounds__(128) void k_score2(const float* __restrict__ ts,
   const float* __restrict__ fc1_w, const float* __restrict__ fc1_b,
   const float* __restrict__ sc_w, const float* __restrict__ sc_b, float* __restrict__ out){
  int t = threadIdx.x; int b = t >> 4, i = t & 15;
  __shared__ float h2[8][17];
  float a = 0.f;
  #pragma unroll
  for (int k=0;k<16;k++) a += ts[b*16+k]*fc1_w[i*16+k];
  a += fc1_b[i];
  h2[b][i] = a > 0.f ? a : 0.f;
  __syncthreads();
  if (t < 8){
    float s = 0.f;
    #pragma unroll
    for (int k=0;k<16;k++) s += h2[t][k]*sc_w[k];
    s += sc_b[0];
    out[t] = 1.0f/(1.0f + expf(-s));
  }
}

extern "C" void kernel_launch(void* const* d_in, const int* in_sizes, int n_in,
                              void* d_out, int out_size, void* d_ws, size_t ws_size,
                              hipStream_t stream){
  const float* f1  = (const float*)d_in[0];
  const float* f2  = (const float*)d_in[1];
  const float* sw1 = (const float*)d_in[2];  const float* sg1 = (const float*)d_in[3];  const float* sb1 = (const float*)d_in[4];
  const float* fw1 = (const float*)d_in[5];  const float* fg1 = (const float*)d_in[6];  const float* fb1 = (const float*)d_in[7];
  const float* sw2 = (const float*)d_in[8];  const float* sg2 = (const float*)d_in[9];  const float* sb2 = (const float*)d_in[10];
  const float* fw2 = (const float*)d_in[11]; const float* fg2 = (const float*)d_in[12]; const float* fb2 = (const float*)d_in[13];
  const float* sw3 = (const float*)d_in[14]; const float* sg3 = (const float*)d_in[15]; const float* sb3 = (const float*)d_in[16];
  const float* fw3 = (const float*)d_in[17]; const float* fg3 = (const float*)d_in[18]; const float* fb3 = (const float*)d_in[19];
  const float* ew  = (const float*)d_in[20]; const float* eg  = (const float*)d_in[21]; const float* eb  = (const float*)d_in[22];
  const float* att_w   = (const float*)d_in[23];
  const float* tn_w    = (const float*)d_in[24];
  const float* tn_wb   = (const float*)d_in[25];
  const float* tn_bias = (const float*)d_in[26];
  const float* fc1_w   = (const float*)d_in[27];
  const float* fc1_b   = (const float*)d_in[28];
  const float* sc_w    = (const float*)d_in[29];
  const float* sc_b    = (const float*)d_in[30];

  float* W    = (float*)d_ws;
  float* T0   = W;                  // 2,097,152  (16384 x <=128)
  float* T1   = W + 2097152;        // 2,097,152
  float* X3S3 = W + 4194304;        // 4,194,304  (16384 x 256)
  float* EMB  = W + 8388608;        // 2,097,152  (16384 x 128)
  float* xx   = W + 10485760;       // 16384
  float* mb   = W + 10502144;       // 2048
  float* gcb  = W + 10504192;       // 2048
  float* scb  = W + 10506240;       // 16384
  float* ep   = W + 10522624;       // 2048
  float* tsb  = W + 10524672;       // 128
  int*   idxb = (int*)(W + 10524800); // 327680 ints
  float* REG  = W + 10852480;       // shared region: S (cB x 1M) / Y (<= 4M)

  size_t ws_floats = ws_size / 4;
  int cB = 16;
  while (cB > 1){
    size_t reg = (size_t)cB * 1048576; if (reg < 4194304) reg = 4194304;
    if (10852480 + reg <= ws_floats) break;
    cB--;
  }

  float* out = (float*)d_out;

  auto edge = [&](const float* xin, int C, int O,
                  const float* w, const float* g, const float* bb,
                  float* xout, int ldo, int ooff){
    k_xx<<<64, 256, 0, stream>>>(xin, xx, C);
    for (int b0=0; b0<16; b0+=cB){
      int nb = 16 - b0; if (nb > cB) nb = cB;
      k_gsym<<<dim3(72, 1, nb), 256, 0, stream>>>(xin, REG, C,
            (long long)1024*C, 1048576ll, b0, xx);
      k_topk<<<1024*nb, 64, 0, stream>>>(REG, idxb, b0);
    }
    k_gthin<<<dim3(2*O/64, 512, 1), 256, 0, stream>>>(xin, w, REG, C, 2*O,
          O, nullptr, nullptr, 0);
    k_edge<<<16384, O, 0, stream>>>(REG, idxb, g, bb, xout, O, ldo, ooff);
  };

  // xyz path (both point clouds as batches 0-7 / 8-15)
  k_extract<<<(8*3*1024+255)/256, 256, 0, stream>>>(f1, T0, 0, 3, 0);
  k_extract<<<(8*3*1024+255)/256, 256, 0, stream>>>(f2, T0, 0, 3, 8);
  edge(T0, 3,   64, sw1, sg1, sb1, T1, 64, 0);
  edge(T1, 64,  64, sw2, sg2, sb2, T0, 64, 0);
  edge(T0, 64, 128, sw3, sg3, sb3, X3S3, 256, 0);    // x3 -> cols 0..127
  // sem path
  k_extract<<<(8*128*1024+255)/256, 256, 0, stream>>>(f1, T0, 3, 128, 0);
  k_extract<<<(8*128*1024+255)/256, 256, 0, stream>>>(f2, T0, 3, 128, 8);
  edge(T0, 128, 64, fw1, fg1, fb1, T1, 64, 0);
  edge(T1, 64,  64, fw2, fg2, fb2, T0, 64, 0);
  edge(T0, 64, 128, fw3, fg3, fb3, X3S3, 256, 128);  // s3 -> cols 128..255
  // combine: emb = lrelu(eg * (X3S3 @ ew^T)/sqrt(1+eps) + eb)
  k_gthin<<<dim3(2, 512, 1), 256, 0, stream>>>(X3S3, ew, EMB, 256, 128,
        0, eg, eb, 1);
  // attention over all 16 batches
  k_mean<<<16, 1024, 0, stream>>>(EMB, mb);
  k_gc<<<16, 128, 0, stream>>>(mb, att_w, gcb);
  k_sc<<<16384, 64, 0, stream>>>(EMB, gcb, scb, out + 8);
  k_pool<<<16, 1024, 0, stream>>>(EMB, scb, ep);

  k_tnet<<<8, 256, 0, stream>>>(ep, ep + 1024, tn_w, tn_wb, tn_bias, tsb);
  k_score2<<<1, 128, 0, stream>>>(tsb, fc1_w, fc1_b, sc_w, sc_b, out);
}